// Round 1
// baseline (720.092 us; speedup 1.0000x reference)
//
#include <hip/hip_runtime.h>

#define NN 100000
#define NE 1600000
#define FIN 256
#define FH 64
#define FC 16

// ---- edge-index dtype robustness: int64 vs int32 detection -----------------
// If the harness delivers int64 (little-endian), the int32 view has every odd
// word == 0 (values < 2^31). Detected once per launch into ws flag.
__global__ void detect_k(const int* __restrict__ ei, int* __restrict__ flag) {
    if (threadIdx.x == 0 && blockIdx.x == 0) {
        int z = (ei[1] == 0) & (ei[3] == 0) & (ei[5] == 0) & (ei[7] == 0);
        *flag = z;   // 1 => int64 layout, 0 => int32 layout
    }
}

__device__ __forceinline__ int eidx(const int* __restrict__ ei, int f, int pos) {
    return f ? ei[2 * pos] : ei[pos];
}

// ---- degree histogram (dst side, self-loop added later as +1) --------------
__global__ void count_k(const int* __restrict__ ei, const int* __restrict__ flag,
                        int* __restrict__ deg) {
    int e = blockIdx.x * 256 + threadIdx.x;
    if (e >= NE) return;
    int f = *flag;
    int d = eidx(ei, f, NE + e);
    atomicAdd(&deg[d], 1);
}

__global__ void dinv_k(const int* __restrict__ deg, float* __restrict__ dinv) {
    int i = blockIdx.x * 256 + threadIdx.x;
    if (i < NN) dinv[i] = rsqrtf((float)(deg[i] + 1));  // +1 self-loop; deg>=1 always
}

// ---- GEMM1: h1[NN][64] = x[NN][256] @ W1[256][64] --------------------------
// 64x64 tile, BK=64, 256 threads, 4x4 register blocking.
// As[k][m] transposed (stride 68: b128-aligned, conflict-free reads).
__global__ __launch_bounds__(256) void gemm1_k(const float* __restrict__ x,
                                               const float* __restrict__ W,
                                               float* __restrict__ h) {
    __shared__ float As[64][68];
    __shared__ float Bs[64][64];
    const int t = threadIdx.x;
    const int r0 = blockIdx.x * 64;
    const int tx4 = (t & 15) * 4;   // col group
    const int ty4 = (t >> 4) * 4;   // row group
    const int lrow = t >> 4;        // 0..15 staging row
    const int lkf = (t & 15) * 4;   // 0..60 staging k-offset

    float acc[4][4] = {};

    for (int k0 = 0; k0 < FIN; k0 += 64) {
        #pragma unroll
        for (int i = 0; i < 4; i++) {
            int row = lrow + 16 * i;           // 0..63
            int gr = r0 + row;
            float4 v = make_float4(0.f, 0.f, 0.f, 0.f);
            if (gr < NN) v = *(const float4*)&x[gr * FIN + k0 + lkf];
            As[lkf + 0][row] = v.x;
            As[lkf + 1][row] = v.y;
            As[lkf + 2][row] = v.z;
            As[lkf + 3][row] = v.w;
            float4 w = *(const float4*)&W[(k0 + row) * FH + lkf];
            *(float4*)&Bs[row][lkf] = w;
        }
        __syncthreads();
        #pragma unroll 8
        for (int kk = 0; kk < 64; kk++) {
            float4 a = *(const float4*)&As[kk][ty4];
            float4 b = *(const float4*)&Bs[kk][tx4];
            float av[4] = {a.x, a.y, a.z, a.w};
            float bv[4] = {b.x, b.y, b.z, b.w};
            #pragma unroll
            for (int i2 = 0; i2 < 4; i2++)
                #pragma unroll
                for (int j2 = 0; j2 < 4; j2++)
                    acc[i2][j2] = fmaf(av[i2], bv[j2], acc[i2][j2]);
        }
        __syncthreads();
    }
    #pragma unroll
    for (int i2 = 0; i2 < 4; i2++) {
        int r = r0 + ty4 + i2;
        if (r < NN)
            *(float4*)&h[r * FH + tx4] =
                make_float4(acc[i2][0], acc[i2][1], acc[i2][2], acc[i2][3]);
    }
}

// ---- agg1 init: b1 + self-loop term ---------------------------------------
__global__ void init1_k(const float* __restrict__ h1, const float* __restrict__ dinv,
                        const float* __restrict__ b1, float* __restrict__ agg) {
    int i = blockIdx.x * 256 + threadIdx.x;     // quad id over NN*16
    if (i >= NN * 16) return;
    int row = i >> 4, q = (i & 15) * 4;
    float di = dinv[row];
    float s = di * di;
    float4 hv = *(const float4*)&h1[row * FH + q];
    float4 bv = *(const float4*)&b1[q];
    float4 o = make_float4(bv.x + hv.x * s, bv.y + hv.y * s,
                           bv.z + hv.z * s, bv.w + hv.w * s);
    *(float4*)&agg[row * FH + q] = o;
}

// ---- scatter layer1: one wave per edge, 64 feats --------------------------
__global__ __launch_bounds__(256) void scatter1_k(const int* __restrict__ ei,
                                                  const int* __restrict__ flag,
                                                  const float* __restrict__ h1,
                                                  const float* __restrict__ dinv,
                                                  float* __restrict__ agg) {
    int e = blockIdx.x * 4 + (threadIdx.x >> 6);
    int lane = threadIdx.x & 63;
    if (e >= NE) return;
    int f = *flag;
    int s = eidx(ei, f, e);
    int d = eidx(ei, f, NE + e);
    float norm = dinv[s] * dinv[d];
    atomicAdd(&agg[d * FH + lane], h1[s * FH + lane] * norm);
}

// ---- GEMM2 + relu: h2[NN][16] = relu(agg1) @ W2[64][16] -------------------
// 192 threads = 192 rows/block; LDS stride 65 (2-way max, free).
__global__ __launch_bounds__(192) void gemm2_k(const float* __restrict__ agg,
                                               const float* __restrict__ W2,
                                               float* __restrict__ h2) {
    __shared__ float a_lds[192 * 65];
    const int t = threadIdx.x;
    const int r0 = blockIdx.x * 192;
    #pragma unroll
    for (int i = 0; i < 16; i++) {
        int fidx = t + 192 * i;                 // 0..3071 float4 slots
        int row = fidx >> 4, kf = (fidx & 15) * 4;
        int gr = r0 + row;
        float4 v = make_float4(0.f, 0.f, 0.f, 0.f);
        if (gr < NN) v = *(const float4*)&agg[gr * FH + kf];
        v.x = fmaxf(v.x, 0.f); v.y = fmaxf(v.y, 0.f);
        v.z = fmaxf(v.z, 0.f); v.w = fmaxf(v.w, 0.f);
        a_lds[row * 65 + kf + 0] = v.x;
        a_lds[row * 65 + kf + 1] = v.y;
        a_lds[row * 65 + kf + 2] = v.z;
        a_lds[row * 65 + kf + 3] = v.w;
    }
    __syncthreads();
    float acc[FC] = {};
    #pragma unroll 4
    for (int k = 0; k < FH; k++) {
        float a = a_lds[t * 65 + k];
        #pragma unroll
        for (int c = 0; c < FC; c++)
            acc[c] = fmaf(a, W2[k * FC + c], acc[c]);   // W2 index wave-uniform -> s_load
    }
    int r = r0 + t;
    if (r < NN) {
        #pragma unroll
        for (int q = 0; q < 4; q++)
            *(float4*)&h2[r * FC + 4 * q] =
                make_float4(acc[4*q], acc[4*q+1], acc[4*q+2], acc[4*q+3]);
    }
}

// ---- out init: b2 + self-loop term ----------------------------------------
__global__ void init2_k(const float* __restrict__ h2, const float* __restrict__ dinv,
                        const float* __restrict__ b2, float* __restrict__ out) {
    int i = blockIdx.x * 256 + threadIdx.x;     // quad id over NN*4
    if (i >= NN * 4) return;
    int row = i >> 2, q = (i & 3) * 4;
    float di = dinv[row];
    float s = di * di;
    float4 hv = *(const float4*)&h2[row * FC + q];
    float4 bv = *(const float4*)&b2[q];
    float4 o = make_float4(bv.x + hv.x * s, bv.y + hv.y * s,
                           bv.z + hv.z * s, bv.w + hv.w * s);
    *(float4*)&out[row * FC + q] = o;
}

// ---- scatter layer2: 16 lanes per edge ------------------------------------
__global__ __launch_bounds__(256) void scatter2_k(const int* __restrict__ ei,
                                                  const int* __restrict__ flag,
                                                  const float* __restrict__ h2,
                                                  const float* __restrict__ dinv,
                                                  float* __restrict__ out) {
    int idx = blockIdx.x * 256 + threadIdx.x;
    int e = idx >> 4, c = idx & 15;
    if (e >= NE) return;
    int f = *flag;
    int s = eidx(ei, f, e);
    int d = eidx(ei, f, NE + e);
    float norm = dinv[s] * dinv[d];
    atomicAdd(&out[d * FC + c], h2[s * FC + c] * norm);
}

extern "C" void kernel_launch(void* const* d_in, const int* in_sizes, int n_in,
                              void* d_out, int out_size, void* d_ws, size_t ws_size,
                              hipStream_t stream) {
    const float* x  = (const float*)d_in[0];
    const int*   ei = (const int*)d_in[1];    // int32 view; layout auto-detected
    const float* W1 = (const float*)d_in[2];
    const float* b1 = (const float*)d_in[3];
    const float* W2 = (const float*)d_in[4];
    const float* b2 = (const float*)d_in[5];
    float* out = (float*)d_out;

    char* ws = (char*)d_ws;
    int*   deg  = (int*)(ws + 0);                          // 400,000 B
    int*   flag = (int*)(ws + 448 * 1024);                 // 4 B
    float* dinv = (float*)(ws + 512 * 1024);               // 400,000 B
    float* h1   = (float*)(ws + 1ull * 1024 * 1024);       // 25.6 MB
    float* agg1 = (float*)(ws + 28ull * 1024 * 1024);      // 25.6 MB
    float* h2   = (float*)(ws + 55ull * 1024 * 1024);      // 6.4 MB

    detect_k<<<1, 64, 0, stream>>>(ei, flag);
    hipMemsetAsync(deg, 0, NN * sizeof(int), stream);
    count_k<<<(NE + 255) / 256, 256, 0, stream>>>(ei, flag, deg);
    dinv_k<<<(NN + 255) / 256, 256, 0, stream>>>(deg, dinv);

    gemm1_k<<<(NN + 63) / 64, 256, 0, stream>>>(x, W1, h1);
    init1_k<<<(NN * 16 + 255) / 256, 256, 0, stream>>>(h1, dinv, b1, agg1);
    scatter1_k<<<NE / 4, 256, 0, stream>>>(ei, flag, h1, dinv, agg1);

    gemm2_k<<<(NN + 191) / 192, 192, 0, stream>>>(agg1, W2, h2);
    init2_k<<<(NN * 4 + 255) / 256, 256, 0, stream>>>(h2, dinv, b2, out);
    scatter2_k<<<(NE * 16) / 256, 256, 0, stream>>>(ei, flag, h2, dinv, out);
}